// Round 1
// baseline (211.098 us; speedup 1.0000x reference)
//
#include <hip/hip_runtime.h>
#include <hip/hip_bf16.h>
#include <math.h>

#define B_  4096u
#define N_  8192
#define D_  128
#define M_  8190u          // negatives per logits row = 2B-2
#define SB_ 25159680u      // S_B = B*(2B-2) - B*(B-1)/2

// ---------------------------------------------------------------------------
// Kernel A: normalize rows of reps=[zjs;zis] and store TRANSPOSED nrepsT[k][row]
// ---------------------------------------------------------------------------
__global__ __launch_bounds__(256) void nt_norm_transpose(
    const float* __restrict__ zis, const float* __restrict__ zjs,
    float* __restrict__ nrepsT) {
  __shared__ float tile[64][129];   // +1 pad: transpose-read conflict-free
  __shared__ float rnorm[64];
  const int t  = threadIdx.x;
  const int i0 = blockIdx.x * 64;

  // load 64 rows x 128 cols (float4 per thread-iter)
  for (int e = t; e < 64 * 32; e += 256) {
    int row = e >> 5, c4 = e & 31;
    int gi  = i0 + row;
    const float* src = (gi < (int)B_) ? (zjs + (size_t)gi * D_)
                                      : (zis + (size_t)(gi - (int)B_) * D_);
    float4 v = *(const float4*)(src + c4 * 4);
    tile[row][c4 * 4 + 0] = v.x;
    tile[row][c4 * 4 + 1] = v.y;
    tile[row][c4 * 4 + 2] = v.z;
    tile[row][c4 * 4 + 3] = v.w;
  }
  __syncthreads();

  {  // 4 threads per row compute sum of squares
    int row = t >> 2, q = t & 3;
    float s = 0.f;
    #pragma unroll
    for (int m = 0; m < 32; ++m) {
      float x = tile[row][q * 32 + m];
      s = fmaf(x, x, s);
    }
    s += __shfl_xor(s, 1, 4);
    s += __shfl_xor(s, 2, 4);
    if (q == 0) rnorm[row] = 1.0f / fmaxf(sqrtf(s), 1e-8f);
  }
  __syncthreads();

  // transposed, normalized write: nrepsT[k][i0+col]
  for (int e = t; e < 64 * 128; e += 256) {
    int k = e >> 6, col = e & 63;
    nrepsT[(size_t)k * N_ + i0 + col] = tile[col][k] * rnorm[col];
  }
}

// ---------------------------------------------------------------------------
// Kernel B: positives + E init.  posl[r] = 2*cos(zjs_r, zis_r); E[r]=exp(posl)
// ---------------------------------------------------------------------------
__global__ __launch_bounds__(256) void nt_posinit(
    const float* __restrict__ nrepsT, float* __restrict__ E,
    float* __restrict__ posl) {
  int r = blockIdx.x * 256 + threadIdx.x;   // 0..B-1
  float s = 0.f;
  #pragma unroll 8
  for (int k = 0; k < D_; ++k)
    s = fmaf(nrepsT[(size_t)k * N_ + r], nrepsT[(size_t)k * N_ + B_ + r], s);
  float pl = 2.0f * s;
  posl[r] = pl;
  E[r]    = __expf(pl);
}

// ---------------------------------------------------------------------------
// Kernel C: upper-triangular tiled GEMM + exp + bucketed accumulation into E
// tile 128x128, 256 threads, 8x8 per thread, K chunked 2x64, LDS 64KB
// ---------------------------------------------------------------------------
__global__ __launch_bounds__(256) void nt_gemm_tile(
    const float* __restrict__ nrepsT, float* __restrict__ E) {
  const int bi = blockIdx.y, bj = blockIdx.x;
  if (bj < bi) return;                       // strict-upper tiles only

  __shared__ float As[64 * 128];             // [k][i]  32KB
  __shared__ float Bs[64 * 128];             // [k][j]  32KB

  const int t    = threadIdx.x;
  const int lane = t & 63, wave = t >> 6;
  const int tx   = t & 15, ty   = t >> 4;
  const int i0   = bi * 128, j0 = bj * 128;

  float acc[8][8];
  #pragma unroll
  for (int a = 0; a < 8; ++a)
    #pragma unroll
    for (int b = 0; b < 8; ++b) acc[a][b] = 0.f;

  for (int kc = 0; kc < 2; ++kc) {
    const int k0 = kc * 64;
    // ---- stage chunk: coalesced global float4 -> linear LDS [k][col] ----
    #pragma unroll
    for (int it = 0; it < 8; ++it) {
      int seg  = wave * 8 + it;              // 0..31, covers 2 k-rows
      int krow = k0 + seg * 2 + (lane >> 5);
      int col4 = (lane & 31) * 4;
      float4 va = *(const float4*)(nrepsT + (size_t)krow * N_ + i0 + col4);
      float4 vb = *(const float4*)(nrepsT + (size_t)krow * N_ + j0 + col4);
      *(float4*)(As + seg * 256 + lane * 4) = va;
      *(float4*)(Bs + seg * 256 + lane * 4) = vb;
    }
    __syncthreads();
    // ---- compute: per k, 4x ds_read_b128 + 64 FMA ----
    #pragma unroll 4
    for (int k = 0; k < 64; ++k) {
      float4 a0 = *(const float4*)(As + k * 128 + ty * 8);
      float4 a1 = *(const float4*)(As + k * 128 + ty * 8 + 4);
      float4 b0 = *(const float4*)(Bs + k * 128 + tx * 4);        // j group 0
      float4 b1 = *(const float4*)(Bs + k * 128 + tx * 4 + 64);   // j group 1
      float av[8] = {a0.x, a0.y, a0.z, a0.w, a1.x, a1.y, a1.z, a1.w};
      float bv[8] = {b0.x, b0.y, b0.z, b0.w, b1.x, b1.y, b1.z, b1.w};
      #pragma unroll
      for (int a = 0; a < 8; ++a)
        #pragma unroll
        for (int b = 0; b < 8; ++b)
          acc[a][b] = fmaf(av[a], bv[b], acc[a][b]);
    }
    __syncthreads();
  }

  // ---- epilogue: flat position -> bucket r, exp, per-row reduce, atomics ----
  const unsigned ib = (unsigned)(i0 + ty * 8);
  #pragma unroll
  for (int a = 0; a < 8; ++a) {
    const unsigned i = ib + a;
    unsigned S;
    if (i <= B_) {
      S = i * (2u * B_ - 2u) - (i * (i - 1u)) / 2u;
    } else {
      unsigned d = i - B_;
      S = SB_ + d * (B_ - 1u) - (d * (d - 1u)) / 2u;
    }
    const unsigned rlo = S / M_;   // every element of sim-row i is in rlo or rlo+1
    float s0 = 0.f, s1 = 0.f;
    #pragma unroll
    for (int g = 0; g < 2; ++g) {
      #pragma unroll
      for (int bb = 0; bb < 4; ++bb) {
        unsigned j = (unsigned)(j0 + g * 64 + tx * 4 + bb);
        bool valid = (j > i) && !((i < B_) && (j == i + B_));
        if (valid) {
          unsigned p = S + (j - i - 1u) - ((i < B_ && j > i + B_) ? 1u : 0u);
          unsigned r = p / M_;
          float e = __expf(2.0f * acc[a][g * 4 + bb]);
          if (r == rlo) s0 += e; else s1 += e;
        }
      }
    }
    // reduce across the 16 tx-lanes of this row (contiguous lanes, width 16)
    #pragma unroll
    for (int m = 8; m >= 1; m >>= 1) {
      s0 += __shfl_xor(s0, m, 16);
      s1 += __shfl_xor(s1, m, 16);
    }
    if (tx == 0) {
      if (s0 != 0.f) atomicAdd(&E[rlo], s0);
      if (s1 != 0.f) atomicAdd(&E[rlo + 1], s1);
    }
  }
}

// ---------------------------------------------------------------------------
// Kernel D: loss = (1/B) * sum_r ( log(E[r]) - posl[r] )
// ---------------------------------------------------------------------------
__global__ __launch_bounds__(256) void nt_finalize(
    const float* __restrict__ E, const float* __restrict__ posl,
    float* __restrict__ out) {
  __shared__ double red[256];
  int t = threadIdx.x;
  double s = 0.0;
  for (int r = t; r < (int)B_; r += 256)
    s += (double)(logf(E[r]) - posl[r]);
  red[t] = s;
  __syncthreads();
  for (int m = 128; m > 0; m >>= 1) {
    if (t < m) red[t] += red[t + m];
    __syncthreads();
  }
  if (t == 0) out[0] = (float)(red[0] / (double)B_);
}

// ---------------------------------------------------------------------------
extern "C" void kernel_launch(void* const* d_in, const int* in_sizes, int n_in,
                              void* d_out, int out_size, void* d_ws, size_t ws_size,
                              hipStream_t stream) {
  const float* zis = (const float*)d_in[0];
  const float* zjs = (const float*)d_in[1];
  float* out = (float*)d_out;

  float* nrepsT = (float*)d_ws;                        // 8192*128 f32 = 4MB
  float* E      = nrepsT + (size_t)N_ * D_;            // B_+16 floats
  float* posl   = E + B_ + 16;                         // B_ floats

  nt_norm_transpose<<<dim3(N_ / 64), 256, 0, stream>>>(zis, zjs, nrepsT);
  nt_posinit      <<<dim3(B_ / 256), 256, 0, stream>>>(nrepsT, E, posl);
  nt_gemm_tile    <<<dim3(64, 64),   256, 0, stream>>>(nrepsT, E);
  nt_finalize     <<<1,              256, 0, stream>>>(E, posl, out);
}

// Round 2
// 127.747 us; speedup vs baseline: 1.6525x; 1.6525x over previous
//
#include <hip/hip_runtime.h>
#include <hip/hip_bf16.h>
#include <math.h>

#define B_  4096u
#define N_  8192
#define D_  128
#define M_  8190u          // negatives per logits row = 2B-2
#define SB_ 25159680u      // S_B = B*(2B-2) - B*(B-1)/2

typedef __attribute__((ext_vector_type(8))) short bf16x8;
typedef __attribute__((ext_vector_type(4))) float f32x4;
typedef __attribute__((ext_vector_type(4))) short short4v;

static __device__ __forceinline__ short f2b(float x) {
  __hip_bfloat16 h = __float2bfloat16(x);
  union { __hip_bfloat16 h; short s; } u; u.h = h; return u.s;
}
static __device__ __forceinline__ float b2f(short b) {
  union { unsigned u; float f; } c;
  c.u = ((unsigned)(unsigned short)b) << 16;
  return c.f;
}

// ---------------------------------------------------------------------------
// Kernel A: normalize rows of reps=[zjs;zis], store bf16 row-major nb[row][k]
// 32 threads per row (float4 each), shfl-reduce width 32.
// ---------------------------------------------------------------------------
__global__ __launch_bounds__(256) void nt_norm(
    const float* __restrict__ zis, const float* __restrict__ zjs,
    short* __restrict__ nb) {
  const int t   = threadIdx.x;
  const int row = blockIdx.x * 8 + (t >> 5);
  const int c   = t & 31;
  const float* src = (row < (int)B_) ? (zjs + (size_t)row * D_)
                                     : (zis + (size_t)(row - (int)B_) * D_);
  float4 v = *(const float4*)(src + c * 4);
  float s = v.x * v.x + v.y * v.y + v.z * v.z + v.w * v.w;
  #pragma unroll
  for (int m = 16; m >= 1; m >>= 1) s += __shfl_xor(s, m, 32);
  float rn = 1.0f / fmaxf(sqrtf(s), 1e-8f);
  short4v o;
  o[0] = f2b(v.x * rn); o[1] = f2b(v.y * rn);
  o[2] = f2b(v.z * rn); o[3] = f2b(v.w * rn);
  *(short4v*)(nb + (size_t)row * D_ + c * 4) = o;
}

// ---------------------------------------------------------------------------
// Kernel B: positives + E init. 16 threads/row, bf16x8 loads, fp32 dot.
// ---------------------------------------------------------------------------
__global__ __launch_bounds__(256) void nt_posinit(
    const short* __restrict__ nb, float* __restrict__ E,
    float* __restrict__ posl) {
  const int idx = blockIdx.x * 256 + threadIdx.x;
  const int r = idx >> 4, c = idx & 15;
  const bf16x8 va = *(const bf16x8*)(nb + (size_t)r * D_ + c * 8);
  const bf16x8 vb = *(const bf16x8*)(nb + (size_t)(r + (int)B_) * D_ + c * 8);
  float s = 0.f;
  #pragma unroll
  for (int e = 0; e < 8; ++e) s = fmaf(b2f(va[e]), b2f(vb[e]), s);
  #pragma unroll
  for (int m = 8; m >= 1; m >>= 1) s += __shfl_xor(s, m, 16);
  if (c == 0) {
    float pl = 2.0f * s;
    posl[r] = pl;
    E[r]    = __expf(pl);
  }
}

// ---------------------------------------------------------------------------
// Kernel C: upper-tri Gram via bf16 MFMA. 128x128 tile, K=128 staged once.
// global_load_lds(16B) w/ both-sides XOR swizzle (slot ^= row&15).
// 4 waves (2x2), 4x4 frags each, 64 MFMA/wave. Epilogue: exp + bucket + atomic.
// ---------------------------------------------------------------------------
__global__ __launch_bounds__(256) void nt_gemm_mfma(
    const short* __restrict__ nb, float* __restrict__ E) {
  // linear upper-triangle decode: t0(bi) = bi*64 - bi*(bi-1)/2
  const int tb = (int)blockIdx.x;
  int bi = (int)((129.0f - sqrtf(16641.0f - 8.0f * (float)tb)) * 0.5f);
  while (bi > 0 && tb < bi * 64 - bi * (bi - 1) / 2) --bi;
  while (tb >= (bi + 1) * 64 - (bi + 1) * bi / 2) ++bi;
  const int bj = bi + (tb - (bi * 64 - bi * (bi - 1) / 2));

  __shared__ short As[128 * 128];   // 32KB, [row][slot^(row&15)] swizzled
  __shared__ short Bs[128 * 128];   // 32KB

  const int t  = threadIdx.x;
  const int i0 = bi * 128, j0 = bj * 128;
  const short* gA = nb + (size_t)i0 * D_;
  const short* gB = nb + (size_t)j0 * D_;

  // ---- stage: linear LDS dest, inverse-swizzled global source ----
  #pragma unroll
  for (int it = 0; it < 8; ++it) {
    int e = it * 256 + t;            // 16B-unit index 0..2047
    int r = e >> 4, s = e & 15;
    int sg = s ^ (r & 15);
    __builtin_amdgcn_global_load_lds(
        (const __attribute__((address_space(1))) void*)(gA + r * D_ + sg * 8),
        (__attribute__((address_space(3))) void*)(As + e * 8), 16, 0, 0);
    __builtin_amdgcn_global_load_lds(
        (const __attribute__((address_space(1))) void*)(gB + r * D_ + sg * 8),
        (__attribute__((address_space(3))) void*)(Bs + e * 8), 16, 0, 0);
  }
  __syncthreads();

  // ---- compute ----
  const int lane = t & 63, wave = t >> 6;
  const int li = lane & 15, hi = lane >> 4;
  const int wrow = (wave >> 1) * 64, wcol = (wave & 1) * 64;

  f32x4 acc[4][4];
  #pragma unroll
  for (int m = 0; m < 4; ++m)
    #pragma unroll
    for (int n = 0; n < 4; ++n) acc[m][n] = (f32x4){0.f, 0.f, 0.f, 0.f};

  #pragma unroll
  for (int ks = 0; ks < 4; ++ks) {
    const int slot = (ks * 4 + hi) ^ li;     // row&15 == li for all frags
    bf16x8 af[4], bfr[4];
    #pragma unroll
    for (int m = 0; m < 4; ++m)
      af[m] = *(const bf16x8*)(As + (wrow + m * 16 + li) * D_ + slot * 8);
    #pragma unroll
    for (int n = 0; n < 4; ++n)
      bfr[n] = *(const bf16x8*)(Bs + (wcol + n * 16 + li) * D_ + slot * 8);
    #pragma unroll
    for (int m = 0; m < 4; ++m)
      #pragma unroll
      for (int n = 0; n < 4; ++n)
        acc[m][n] = __builtin_amdgcn_mfma_f32_16x16x32_bf16(
            af[m], bfr[n], acc[m][n], 0, 0, 0);
  }

  // ---- epilogue: bucket + exp + 16-lane reduce + atomics ----
  #pragma unroll
  for (int m = 0; m < 4; ++m) {
    #pragma unroll
    for (int rg = 0; rg < 4; ++rg) {
      const unsigned i = (unsigned)(i0 + wrow + m * 16 + hi * 4 + rg);
      unsigned S;
      if (i <= B_) {
        S = i * (2u * B_ - 2u) - (i * (i - 1u)) / 2u;
      } else {
        unsigned d = i - B_;
        S = SB_ + d * (B_ - 1u) - (d * (d - 1u)) / 2u;
      }
      const unsigned rlo = S / M_;           // const-divisor -> magic mul
      const unsigned Sh  = (rlo + 1u) * M_;  // bucket boundary
      float s0 = 0.f, s1 = 0.f;
      #pragma unroll
      for (int n = 0; n < 4; ++n) {
        const unsigned j = (unsigned)(j0 + wcol + n * 16 + li);
        const bool valid = (j > i) && !((i < B_) && (j == i + B_));
        if (valid) {
          unsigned p = S + (j - i - 1u) - ((i < B_ && j > i + B_) ? 1u : 0u);
          float e = __expf(2.0f * acc[m][n][rg]);
          if (p < Sh) s0 += e; else s1 += e;
        }
      }
      #pragma unroll
      for (int msk = 8; msk >= 1; msk >>= 1) {
        s0 += __shfl_xor(s0, msk, 16);
        s1 += __shfl_xor(s1, msk, 16);
      }
      if (li == 0) {
        if (s0 != 0.f) atomicAdd(&E[rlo], s0);
        if (s1 != 0.f) atomicAdd(&E[rlo + 1], s1);
      }
    }
  }
}

// ---------------------------------------------------------------------------
// Kernel D: loss = (1/B) * sum_r ( log(E[r]) - posl[r] )
// ---------------------------------------------------------------------------
__global__ __launch_bounds__(256) void nt_finalize(
    const float* __restrict__ E, const float* __restrict__ posl,
    float* __restrict__ out) {
  __shared__ double red[256];
  int t = threadIdx.x;
  double s = 0.0;
  for (int r = t; r < (int)B_; r += 256)
    s += (double)(logf(E[r]) - posl[r]);
  red[t] = s;
  __syncthreads();
  for (int m = 128; m > 0; m >>= 1) {
    if (t < m) red[t] += red[t + m];
    __syncthreads();
  }
  if (t == 0) out[0] = (float)(red[0] / (double)B_);
}

// ---------------------------------------------------------------------------
extern "C" void kernel_launch(void* const* d_in, const int* in_sizes, int n_in,
                              void* d_out, int out_size, void* d_ws, size_t ws_size,
                              hipStream_t stream) {
  const float* zis = (const float*)d_in[0];
  const float* zjs = (const float*)d_in[1];
  float* out = (float*)d_out;

  short* nb   = (short*)d_ws;                              // 8192*128 bf16 = 2MB
  float* E    = (float*)((char*)d_ws + (size_t)N_ * D_ * sizeof(short));
  float* posl = E + B_ + 16;

  nt_norm     <<<dim3(N_ / 8),        256, 0, stream>>>(zis, zjs, nb);
  nt_posinit  <<<dim3(B_ * 16 / 256), 256, 0, stream>>>(nb, E, posl);
  nt_gemm_mfma<<<dim3(2080),          256, 0, stream>>>(nb, E);
  nt_finalize <<<dim3(1),             256, 0, stream>>>(E, posl, out);
}

// Round 3
// 97.870 us; speedup vs baseline: 2.1569x; 1.3053x over previous
//
#include <hip/hip_runtime.h>
#include <hip/hip_bf16.h>
#include <math.h>

#define B_  4096u
#define N_  8192
#define D_  128
#define M_  8190u          // negatives per logits row = 2B-2
#define SB_ 25159680u      // S_B = B*(2B-2) - B*(B-1)/2
#define NT_ 2080           // number of upper-triangle 128x128 tiles

typedef __attribute__((ext_vector_type(8))) short bf16x8;
typedef __attribute__((ext_vector_type(4))) float f32x4;
typedef __attribute__((ext_vector_type(4))) short short4v;

static __device__ __forceinline__ short f2b(float x) {
  __hip_bfloat16 h = __float2bfloat16(x);
  union { __hip_bfloat16 h; short s; } u; u.h = h; return u.s;
}
static __device__ __forceinline__ float b2f(short b) {
  union { unsigned u; float f; } c;
  c.u = ((unsigned)(unsigned short)b) << 16;
  return c.f;
}
// cumulative flat-count of strict-upper (minus positives) elements before row i
static __device__ __forceinline__ unsigned rowS(unsigned i) {
  if (i <= B_) return i * (2u * B_ - 2u) - (i * (i - 1u)) / 2u;
  unsigned d = i - B_;
  return SB_ + d * (B_ - 1u) - (d * (d - 1u)) / 2u;
}

// ---------------------------------------------------------------------------
// Kernel A: normalize rows of reps=[zjs;zis], store bf16 row-major nb[row][k]
// ---------------------------------------------------------------------------
__global__ __launch_bounds__(256) void nt_norm(
    const float* __restrict__ zis, const float* __restrict__ zjs,
    short* __restrict__ nb) {
  const int t   = threadIdx.x;
  const int row = blockIdx.x * 8 + (t >> 5);
  const int c   = t & 31;
  const float* src = (row < (int)B_) ? (zjs + (size_t)row * D_)
                                     : (zis + (size_t)(row - (int)B_) * D_);
  float4 v = *(const float4*)(src + c * 4);
  float s = v.x * v.x + v.y * v.y + v.z * v.z + v.w * v.w;
  #pragma unroll
  for (int m = 16; m >= 1; m >>= 1) s += __shfl_xor(s, m, 32);
  float rn = 1.0f / fmaxf(sqrtf(s), 1e-8f);
  short4v o;
  o[0] = f2b(v.x * rn); o[1] = f2b(v.y * rn);
  o[2] = f2b(v.z * rn); o[3] = f2b(v.w * rn);
  *(short4v*)(nb + (size_t)row * D_ + c * 4) = o;
}

// ---------------------------------------------------------------------------
// Kernel B: positives. posl[r] = 2*cos(zjs_r, zis_r). 16 threads/row.
// ---------------------------------------------------------------------------
__global__ __launch_bounds__(256) void nt_posinit(
    const short* __restrict__ nb, float* __restrict__ posl) {
  const int idx = blockIdx.x * 256 + threadIdx.x;
  const int r = idx >> 4, c = idx & 15;
  const bf16x8 va = *(const bf16x8*)(nb + (size_t)r * D_ + c * 8);
  const bf16x8 vb = *(const bf16x8*)(nb + (size_t)(r + (int)B_) * D_ + c * 8);
  float s = 0.f;
  #pragma unroll
  for (int e = 0; e < 8; ++e) s = fmaf(b2f(va[e]), b2f(vb[e]), s);
  #pragma unroll
  for (int m = 8; m >= 1; m >>= 1) s += __shfl_xor(s, m, 16);
  if (c == 0) posl[r] = 2.0f * s;
}

// ---------------------------------------------------------------------------
// Kernel C: upper-tri Gram via bf16 MFMA, 128x128 tile, K=128 staged once.
// Epilogue: exp + bucket-split + 16-lane reduce + PLAIN float2 store (no atomics).
// part layout: part[(tb*2 + jhalf)*128 + localrow] = (sum_lo, sum_hi)
// ---------------------------------------------------------------------------
__global__ __launch_bounds__(256) void nt_gemm_mfma(
    const short* __restrict__ nb, float2* __restrict__ part) {
  const int tb = (int)blockIdx.x;
  int bi = (int)((129.0f - sqrtf(16641.0f - 8.0f * (float)tb)) * 0.5f);
  while (bi > 0 && tb < bi * 64 - bi * (bi - 1) / 2) --bi;
  while (tb >= (bi + 1) * 64 - (bi + 1) * bi / 2) ++bi;
  const int t0b = bi * 64 - bi * (bi - 1) / 2;
  const int bj  = bi + (tb - t0b);

  __shared__ short As[128 * 128];   // 32KB, [row][slot^(row&15)] swizzled
  __shared__ short Bs[128 * 128];   // 32KB

  const int t  = threadIdx.x;
  const int i0 = bi * 128, j0 = bj * 128;
  const short* gA = nb + (size_t)i0 * D_;
  const short* gB = nb + (size_t)j0 * D_;

  // ---- stage: linear LDS dest, inverse-swizzled global source ----
  #pragma unroll
  for (int it = 0; it < 8; ++it) {
    int e = it * 256 + t;            // 16B-unit index 0..2047
    int r = e >> 4, s = e & 15;
    int sg = s ^ (r & 15);
    __builtin_amdgcn_global_load_lds(
        (const __attribute__((address_space(1))) void*)(gA + r * D_ + sg * 8),
        (__attribute__((address_space(3))) void*)(As + e * 8), 16, 0, 0);
    __builtin_amdgcn_global_load_lds(
        (const __attribute__((address_space(1))) void*)(gB + r * D_ + sg * 8),
        (__attribute__((address_space(3))) void*)(Bs + e * 8), 16, 0, 0);
  }
  __syncthreads();

  // ---- compute ----
  const int lane = t & 63, wave = t >> 6;
  const int li = lane & 15, hi = lane >> 4;
  const int wrow = (wave >> 1) * 64, wcol = (wave & 1) * 64;

  f32x4 acc[4][4];
  #pragma unroll
  for (int m = 0; m < 4; ++m)
    #pragma unroll
    for (int n = 0; n < 4; ++n) acc[m][n] = (f32x4){0.f, 0.f, 0.f, 0.f};

  #pragma unroll
  for (int ks = 0; ks < 4; ++ks) {
    const int slot = (ks * 4 + hi) ^ li;
    bf16x8 af[4], bfr[4];
    #pragma unroll
    for (int m = 0; m < 4; ++m)
      af[m] = *(const bf16x8*)(As + (wrow + m * 16 + li) * D_ + slot * 8);
    #pragma unroll
    for (int n = 0; n < 4; ++n)
      bfr[n] = *(const bf16x8*)(Bs + (wcol + n * 16 + li) * D_ + slot * 8);
    #pragma unroll
    for (int m = 0; m < 4; ++m)
      #pragma unroll
      for (int n = 0; n < 4; ++n)
        acc[m][n] = __builtin_amdgcn_mfma_f32_16x16x32_bf16(
            af[m], bfr[n], acc[m][n], 0, 0, 0);
  }

  // ---- epilogue: bucket-split sums per row, store partials ----
  #pragma unroll
  for (int m = 0; m < 4; ++m) {
    #pragma unroll
    for (int rg = 0; rg < 4; ++rg) {
      const int lrow = wrow + m * 16 + hi * 4 + rg;
      const unsigned i = (unsigned)(i0 + lrow);
      const unsigned S   = rowS(i);
      const unsigned rlo = S / M_;             // const-divisor -> magic mul
      const unsigned Sh  = (rlo + 1u) * M_;    // bucket boundary
      float s0 = 0.f, s1 = 0.f;
      #pragma unroll
      for (int n = 0; n < 4; ++n) {
        const unsigned j = (unsigned)(j0 + wcol + n * 16 + li);
        const bool valid = (j > i) && !((i < B_) && (j == i + B_));
        if (valid) {
          unsigned p = S + (j - i - 1u) - ((i < B_ && j > i + B_) ? 1u : 0u);
          float e = __expf(2.0f * acc[m][n][rg]);
          if (p < Sh) s0 += e; else s1 += e;
        }
      }
      #pragma unroll
      for (int msk = 8; msk >= 1; msk >>= 1) {
        s0 += __shfl_xor(s0, msk, 16);
        s1 += __shfl_xor(s1, msk, 16);
      }
      if (li == 0) {
        part[((size_t)tb * 2 + (wave & 1)) * 128 + lrow] = make_float2(s0, s1);
      }
    }
  }
}

// ---------------------------------------------------------------------------
// Kernel D: per-row reduction of partials. One wave per sim-row.
// rowsum[i] = (sum into bucket rlo(i), sum into bucket rlo(i)+1)
// ---------------------------------------------------------------------------
__global__ __launch_bounds__(256) void nt_rowreduce(
    const float2* __restrict__ part, float2* __restrict__ rowsum) {
  const int wave = threadIdx.x >> 6, lane = threadIdx.x & 63;
  const int i = blockIdx.x * 4 + wave;          // global sim-row
  const int bi = i >> 7, lrow = i & 127;
  const int t0 = bi * 64 - bi * (bi - 1) / 2;
  const int cnt = 2 * (64 - bi);                // (block, jhalf) slots for this row
  float s0 = 0.f, s1 = 0.f;
  for (int c = lane; c < cnt; c += 64) {
    const int tb = t0 + (c >> 1), half = c & 1;
    float2 v = part[((size_t)tb * 2 + half) * 128 + lrow];
    s0 += v.x; s1 += v.y;
  }
  #pragma unroll
  for (int m = 32; m >= 1; m >>= 1) {
    s0 += __shfl_xor(s0, m, 64);
    s1 += __shfl_xor(s1, m, 64);
  }
  if (lane == 0) rowsum[i] = make_float2(s0, s1);
}

// ---------------------------------------------------------------------------
// Kernel E: finalize (one block). Build E buckets in LDS, then loss.
// ---------------------------------------------------------------------------
__global__ __launch_bounds__(256) void nt_finalize(
    const float2* __restrict__ rowsum, const float* __restrict__ posl,
    float* __restrict__ out) {
  __shared__ float Eb[4104];     // 4096 buckets + slack for rlo up to 4097
  __shared__ double red[256];
  const int t = threadIdx.x;

  for (int r = t; r < 4104; r += 256)
    Eb[r] = (r < 4096) ? __expf(posl[r]) : 0.f;
  __syncthreads();

  for (int i = t; i < N_; i += 256) {
    const unsigned S   = rowS((unsigned)i);
    const unsigned rlo = S / M_;
    float2 v = rowsum[i];
    atomicAdd(&Eb[rlo], v.x);        // LDS atomics (fast, on-CU)
    atomicAdd(&Eb[rlo + 1], v.y);
  }
  __syncthreads();

  double s = 0.0;
  for (int r = t; r < (int)B_; r += 256)
    s += (double)(logf(Eb[r]) - posl[r]);
  red[t] = s;
  __syncthreads();
  for (int m = 128; m > 0; m >>= 1) {
    if (t < m) red[t] += red[t + m];
    __syncthreads();
  }
  if (t == 0) out[0] = (float)(red[0] / (double)B_);
}

// ---------------------------------------------------------------------------
extern "C" void kernel_launch(void* const* d_in, const int* in_sizes, int n_in,
                              void* d_out, int out_size, void* d_ws, size_t ws_size,
                              hipStream_t stream) {
  const float* zis = (const float*)d_in[0];
  const float* zjs = (const float*)d_in[1];
  float* out = (float*)d_out;

  char* ws = (char*)d_ws;
  short*  nb     = (short*)ws;                 // 2 MB
  float*  posl   = (float*)(ws + 2097152);     // 16 KB
  float2* part   = (float2*)(ws + 2097152 + 16384);            // 2080*2*128*8 = 4.26 MB
  float2* rowsum = (float2*)(ws + 2097152 + 16384 + 4259840);  // 64 KB

  nt_norm     <<<dim3(N_ / 8),        256, 0, stream>>>(zis, zjs, nb);
  nt_posinit  <<<dim3(B_ * 16 / 256), 256, 0, stream>>>(nb, posl);
  nt_gemm_mfma<<<dim3(NT_),           256, 0, stream>>>(nb, part);
  nt_rowreduce<<<dim3(N_ / 4),        256, 0, stream>>>(part, rowsum);
  nt_finalize <<<dim3(1),             256, 0, stream>>>(rowsum, posl, out);
}